// Round 15
// baseline (219.810 us; speedup 1.0000x reference)
//
#include <hip/hip_runtime.h>
#include <stdint.h>

#define N_VOX   (1 << 19)
#define CIN     64
#define COUT    128
#define BIN_SHIFT 3
#define BINS    (1 << 20)          // (4*8*512*512) >> 3, lambda = 0.5/bin
#define OFF_BITS 4                 // intra-bin arrival offset
#define BPB     256                // bins per k_mega block (~128 positions)
#define NTILES  1024               // scan tiles (1024 bins each)
#define PCAP    512                // max positions per mega block (Poisson(128))
#define EPSV    1e-5f

typedef float f32x4 __attribute__((ext_vector_type(4)));

// MEASUREMENT ROUND (differential probe): r14 kernel + every d_out store is
// mirrored by an identical plain dense store into an unused 277-MB d_ws
// region. Delta vs r14's 179.4us isolates my-kernel dense-write rate to d_ws:
// +~45us => d_out is the slow buffer (uncached theory); +~100us => universal
// ~2.8 TB/s store wall for compute kernels.
//
// ws ints: hist[BINS] | ticket(1)+pad(3) | tiles[2*NTILES] | cursor[BINS]
//          | packed[N] | recs[2*N] | ... | mirror at ws+(1<<22) ints

#define CLR_INTS (BINS + 4 + 2 * NTILES)
#define CLR_4    (CLR_INTS / 4 + 1)

__global__ void k_clear(int* __restrict__ p) {
    int t = blockIdx.x * 256 + threadIdx.x;
    if (t * 4 < CLR_INTS) *(int4*)&p[t * 4] = make_int4(0, 0, 0, 0);
}

__global__ void k_hist(const int* __restrict__ idx, unsigned* __restrict__ packed,
                       int* __restrict__ hist) {
    int j = blockIdx.x * 256 + threadIdx.x;
    int4 v = *(const int4*)&idx[j * 4];
    int lin = ((v.x * 8 + v.y) * 512 + v.z) * 512 + v.w;
    int off = atomicAdd(&hist[lin >> BIN_SHIFT], 1);
    packed[j] = ((unsigned)lin << OFF_BITS) | (unsigned)off;
}

__global__ __launch_bounds__(256) void k_scan(
    const int* __restrict__ hist, int* __restrict__ cursor,
    unsigned long long* __restrict__ tiles, int* __restrict__ ticket) {
    __shared__ int stile;
    __shared__ int wsums[4];
    __shared__ int sprefix;
    int tid = threadIdx.x;
    if (tid == 0) stile = atomicAdd(ticket, 1);
    __syncthreads();
    int tile = stile;
    int base = tile * 1024 + tid * 4;
    int4 v = *(const int4*)&hist[base];
    int t3 = v.x + v.y + v.z + v.w;
    int lane = tid & 63, w = tid >> 6;
    int incl = t3;
    #pragma unroll
    for (int off = 1; off < 64; off <<= 1) {
        int u = __shfl_up(incl, off);
        if (lane >= off) incl += u;
    }
    if (lane == 63) wsums[w] = incl;
    __syncthreads();
    int woff = (w > 0 ? wsums[0] : 0) + (w > 1 ? wsums[1] : 0) + (w > 2 ? wsums[2] : 0);
    int total = wsums[0] + wsums[1] + wsums[2] + wsums[3];
    int texcl = woff + incl - t3;
    if (tid == 0) {
        unsigned long long st = (tile == 0) ? 2ull : 1ull;
        atomicExch(&tiles[tile], (st << 40) | (unsigned long long)(unsigned)total);
        int pfx = 0;
        if (tile > 0) {
            int p = tile - 1;
            while (true) {
                unsigned long long d = atomicAdd(&tiles[p], 0ull);
                unsigned long long st2 = d >> 40;
                if (st2 == 0) { __builtin_amdgcn_s_sleep(2); continue; }
                pfx += (int)(unsigned)(d & 0xFFFFFFFFull);
                if (st2 == 2ull) break;
                p--;
            }
            atomicExch(&tiles[tile],
                       (2ull << 40) | (unsigned long long)(unsigned)(pfx + total));
        }
        sprefix = pfx;
    }
    __syncthreads();
    int prefix = sprefix + texcl;
    int4 e;
    e.x = prefix;
    e.y = prefix + v.x;
    e.z = prefix + v.x + v.y;
    e.w = prefix + v.x + v.y + v.z;
    *(int4*)&cursor[base] = e;
}

__global__ void k_scatter(const unsigned* __restrict__ packed, const int* __restrict__ cursor,
                          uint2* __restrict__ recs) {
    int j = blockIdx.x * 256 + threadIdx.x;
    unsigned p = packed[j];
    unsigned lin = p >> OFF_BITS;
    int pos = cursor[lin >> BIN_SHIFT] + (int)(p & ((1u << OFF_BITS) - 1u));
    recs[pos] = make_uint2(lin, (unsigned)j);
}

// ---------- fused fixup + GEMM + LN + dense single-pass output (+mirror) ----
__global__ __launch_bounds__(256) void k_mega(
    const float* __restrict__ feats, const float* __restrict__ weight,
    const float* __restrict__ gamma, const float* __restrict__ beta,
    const int* __restrict__ hist, const int* __restrict__ cursor,
    const uint2* __restrict__ recs, float* __restrict__ out,
    float* __restrict__ mir) {
    __shared__ float featb[4][8][CIN];
    __shared__ float sstage[32][COUT];
    __shared__ unsigned slin[PCAP];
    __shared__ int sperm[PCAP];
    __shared__ unsigned short vpos[PCAP];
    __shared__ unsigned char sslot[PCAP];
    __shared__ int wsum[4];

    int tid = threadIdx.x;
    int w = tid >> 6, lane = tid & 63;
    int B0 = blockIdx.x * BPB;
    int p0 = cursor[B0];
    int p1 = (B0 + BPB < BINS) ? cursor[B0 + BPB] : N_VOX;
    int npos = p1 - p0;

    for (int lp = tid; lp < npos; lp += 256) {
        uint2 r = recs[p0 + lp];
        slin[lp] = r.x;
        sperm[lp] = (int)r.y;
        sslot[lp] = 0xFFu;
    }
    __syncthreads();

    int b = B0 + tid;
    int c = hist[b];
    int ls = cursor[b] - p0;
    if (c >= 2) {
        for (int i = 1; i < c; i++) {
            unsigned lj = slin[ls + i];
            int pj = sperm[ls + i];
            unsigned long long kj = ((unsigned long long)lj << 19) | (unsigned)pj;
            int m = i - 1;
            while (m >= 0) {
                unsigned lm = slin[ls + m];
                int pm = sperm[ls + m];
                unsigned long long km = ((unsigned long long)lm << 19) | (unsigned)pm;
                if (km <= kj) break;
                slin[ls + m + 1] = lm;
                sperm[ls + m + 1] = pm;
                m--;
            }
            slin[ls + m + 1] = lj;
            sperm[ls + m + 1] = pj;
        }
    }
    int myv = 0;
    for (int i = 0; i < c; i++)
        myv += ((slin[ls + i] & 0x201u) == 0u) ? 1 : 0;
    int incl = myv;
    #pragma unroll
    for (int off = 1; off < 64; off <<= 1) {
        int u = __shfl_up(incl, off);
        if (lane >= off) incl += u;
    }
    if (lane == 63) wsum[w] = incl;
    __syncthreads();
    int s0 = wsum[0], s1 = wsum[1], s2 = wsum[2], s3 = wsum[3];
    int nv = s0 + s1 + s2 + s3;
    int woff = (w > 0 ? s0 : 0) + (w > 1 ? s1 : 0) + (w > 2 ? s2 : 0);
    int basev = woff + incl - myv;
    for (int i = 0; i < c; i++) {
        int lp = ls + i;
        if ((slin[lp] & 0x201u) == 0u) {
            vpos[basev] = (unsigned short)lp;
            sslot[lp] = (unsigned char)(basev & 31);
            basev++;
        }
    }
    __syncthreads();

    int half = lane >> 5, l32 = lane & 31;
    float* oidx = out + (size_t)N_VOX * COUT;
    float* midx = mir + (size_t)N_VOX * COUT;
    f32x4 z = {0.f, 0.f, 0.f, 0.f};

    if (nv == 0) {
        f32x4 mi = {-1.f, -1.f, -1.f, -1.f};
        for (int lp = w * 2 + half; lp < npos; lp += 8) {
            size_t o = (size_t)(p0 + lp) * COUT + l32 * 4;
            *(f32x4*)&out[o] = z;
            *(f32x4*)&mir[o] = z;      // mirror probe
        }
        for (int lp = tid; lp < npos; lp += 256) {
            size_t o = (size_t)(p0 + lp) * 4;
            *(f32x4*)&oidx[o] = mi;
            *(f32x4*)&midx[o] = mi;    // mirror probe
        }
        return;
    }

    const f32x4* Wg4 = (const f32x4*)weight;
    f32x4 gv = *(const f32x4*)&gamma[l32 * 4];
    f32x4 bv = *(const f32x4*)&beta[l32 * 4];
    int wcur = 0;

    for (int m0 = 0; m0 < nv; m0 += 32) {
        int mb = m0 + w * 8;
        if (mb < nv) {
            #pragma unroll
            for (int i = 0; i < 8; i++) {
                int m = mb + i;
                int lp = vpos[(m < nv) ? m : 0];
                featb[w][i][lane] = feats[(size_t)sperm[lp] * CIN + lane];
            }
            f32x4 acc[4];
            #pragma unroll
            for (int i = 0; i < 4; i++) acc[i] = z;
            #pragma unroll 4
            for (int k0 = 0; k0 < CIN; k0 += 4) {
                f32x4 wv0 = Wg4[(k0 + 0) * 32 + l32];
                f32x4 wv1 = Wg4[(k0 + 1) * 32 + l32];
                f32x4 wv2 = Wg4[(k0 + 2) * 32 + l32];
                f32x4 wv3 = Wg4[(k0 + 3) * 32 + l32];
                #pragma unroll
                for (int ii = 0; ii < 4; ii++) {
                    float4 f = *(float4*)&featb[w][2 * ii + half][k0];
                    acc[ii] += f.x * wv0;
                    acc[ii] += f.y * wv1;
                    acc[ii] += f.z * wv2;
                    acc[ii] += f.w * wv3;
                }
            }
            #pragma unroll
            for (int ii = 0; ii < 4; ii++) {
                int m = mb + 2 * ii + half;
                f32x4 a = acc[ii];
                float sm = a.x + a.y + a.z + a.w;
                float sq = a.x * a.x + a.y * a.y + a.z * a.z + a.w * a.w;
                #pragma unroll
                for (int off = 16; off > 0; off >>= 1) {
                    sm += __shfl_xor(sm, off);
                    sq += __shfl_xor(sq, off);
                }
                float mean = sm * (1.0f / COUT);
                float var  = fmaxf(sq * (1.0f / COUT) - mean * mean, 0.0f);
                float rstd = rsqrtf(var + EPSV);
                if (m < nv) {
                    f32x4 o = (a - mean) * rstd * gv + bv;
                    *(f32x4*)&sstage[m & 31][l32 * 4] = o;
                }
            }
        }
        __syncthreads();

        int end = (m0 + 32 < nv) ? vpos[m0 + 32] : npos;
        for (int lp = wcur + w * 2 + half; lp < end; lp += 8) {
            int sl = sslot[lp];
            f32x4 o = (sl != 0xFF) ? *(f32x4*)&sstage[sl][l32 * 4] : z;
            size_t off = (size_t)(p0 + lp) * COUT + l32 * 4;
            *(f32x4*)&out[off] = o;
            *(f32x4*)&mir[off] = o;    // mirror probe
        }
        for (int lp = wcur + tid; lp < end; lp += 256) {
            f32x4 ni;
            if (sslot[lp] != 0xFF) {
                unsigned lin = slin[lp];
                ni.x = (float)(lin >> 21);
                ni.y = (float)((lin >> 18) & 7u);
                ni.z = (float)(((lin >> 9) & 511u) >> 1);
                ni.w = (float)((lin & 511u) >> 1);
            } else {
                ni = (f32x4){-1.f, -1.f, -1.f, -1.f};
            }
            size_t off = (size_t)(p0 + lp) * 4;
            *(f32x4*)&oidx[off] = ni;
            *(f32x4*)&midx[off] = ni;  // mirror probe
        }
        wcur = end;
        __syncthreads();
    }
}

extern "C" void kernel_launch(void* const* d_in, const int* in_sizes, int n_in,
                              void* d_out, int out_size, void* d_ws, size_t ws_size,
                              hipStream_t stream) {
    const float* feats  = (const float*)d_in[0];
    const int*   idx    = (const int*)d_in[1];
    const float* weight = (const float*)d_in[2];
    const float* gamma  = (const float*)d_in[3];
    const float* beta   = (const float*)d_in[4];
    float* out = (float*)d_out;

    int* ws = (int*)d_ws;
    int*                hist   = ws;                         // BINS
    int*                ticket = ws + BINS;                  // 1 (+3 pad)
    unsigned long long* tiles  = (unsigned long long*)(ws + BINS + 4);  // NTILES
    int*                cursor = ws + BINS + 4 + 2 * NTILES; // BINS
    unsigned*           packed = (unsigned*)(cursor + BINS); // N
    uint2*              recs   = (uint2*)(packed + N_VOX);   // N x 8B
    float*              mirror = (float*)(ws + (1 << 22));   // 277 MB probe region

    k_clear<<<(CLR_4 + 255) / 256, 256, 0, stream>>>(ws);
    k_hist<<<N_VOX / 256, 256, 0, stream>>>(idx, packed, hist);
    k_scan<<<NTILES, 256, 0, stream>>>(hist, cursor, tiles, ticket);
    k_scatter<<<N_VOX / 256, 256, 0, stream>>>(packed, cursor, recs);
    k_mega<<<BINS / BPB, 256, 0, stream>>>(feats, weight, gamma, beta,
                                           hist, cursor, recs, out, mirror);
}

// Round 16
// 164.935 us; speedup vs baseline: 1.3327x; 1.3327x over previous
//
#include <hip/hip_runtime.h>
#include <stdint.h>

#define N_VOX   (1 << 19)
#define CIN     64
#define COUT    128
#define BIN_SHIFT 3
#define BINS    (1 << 20)          // (4*8*512*512) >> 3, lambda = 0.5/bin
#define OFF_BITS 4                 // intra-bin arrival offset
#define BPB     512                // bins per k_mega block (~256 positions)
#define NBLK    (BINS / BPB)       // 2048 blocks
#define NTILES  1024               // scan tiles (1024 bins each)
#define PCAP    1024               // max positions per mega block (Poisson(256))
#define EPSV    1e-5f

typedef float f32x4 __attribute__((ext_vector_type(4)));

static __device__ __forceinline__ void nt_store4(float* p, f32x4 v) {
    __builtin_nontemporal_store(v, (f32x4*)p);
}

// Established (r15 probe): d_out stores cap ~2.8 TB/s regardless of pattern;
// d_ws absorbs ~6.9 TB/s. Floor: 276 MB d_out / 2.8 ~= 99 us. Design: write
// every d_out byte exactly once, issue stores as early as possible, hide all
// gather/compute under the drain. No staging, 3 barriers/block, 18 KB LDS.
//
// ws ints: hist[BINS] | ticket(1)+pad(3) | tiles[2*NTILES] | cursor[BINS]
//          | packed[N] | recs[2*N]

#define CLR_INTS (BINS + 4 + 2 * NTILES)
#define CLR_4    (CLR_INTS / 4 + 1)

__global__ void k_clear(int* __restrict__ p) {
    int t = blockIdx.x * 256 + threadIdx.x;
    if (t * 4 < CLR_INTS) *(int4*)&p[t * 4] = make_int4(0, 0, 0, 0);
}

__global__ void k_hist(const int* __restrict__ idx, unsigned* __restrict__ packed,
                       int* __restrict__ hist) {
    int j = blockIdx.x * 256 + threadIdx.x;
    int4 v = *(const int4*)&idx[j * 4];
    int lin = ((v.x * 8 + v.y) * 512 + v.z) * 512 + v.w;
    int off = atomicAdd(&hist[lin >> BIN_SHIFT], 1);
    packed[j] = ((unsigned)lin << OFF_BITS) | (unsigned)off;
}

// single-kernel exclusive scan, decoupled lookback, ticket-ordered tiles.
__global__ __launch_bounds__(256) void k_scan(
    const int* __restrict__ hist, int* __restrict__ cursor,
    unsigned long long* __restrict__ tiles, int* __restrict__ ticket) {
    __shared__ int stile;
    __shared__ int wsums[4];
    __shared__ int sprefix;
    int tid = threadIdx.x;
    if (tid == 0) stile = atomicAdd(ticket, 1);
    __syncthreads();
    int tile = stile;
    int base = tile * 1024 + tid * 4;
    int4 v = *(const int4*)&hist[base];
    int t3 = v.x + v.y + v.z + v.w;
    int lane = tid & 63, w = tid >> 6;
    int incl = t3;
    #pragma unroll
    for (int off = 1; off < 64; off <<= 1) {
        int u = __shfl_up(incl, off);
        if (lane >= off) incl += u;
    }
    if (lane == 63) wsums[w] = incl;
    __syncthreads();
    int woff = (w > 0 ? wsums[0] : 0) + (w > 1 ? wsums[1] : 0) + (w > 2 ? wsums[2] : 0);
    int total = wsums[0] + wsums[1] + wsums[2] + wsums[3];
    int texcl = woff + incl - t3;
    if (tid == 0) {
        unsigned long long st = (tile == 0) ? 2ull : 1ull;
        atomicExch(&tiles[tile], (st << 40) | (unsigned long long)(unsigned)total);
        int pfx = 0;
        if (tile > 0) {
            int p = tile - 1;
            while (true) {
                unsigned long long d = atomicAdd(&tiles[p], 0ull);
                unsigned long long st2 = d >> 40;
                if (st2 == 0) { __builtin_amdgcn_s_sleep(2); continue; }
                pfx += (int)(unsigned)(d & 0xFFFFFFFFull);
                if (st2 == 2ull) break;
                p--;
            }
            atomicExch(&tiles[tile],
                       (2ull << 40) | (unsigned long long)(unsigned)(pfx + total));
        }
        sprefix = pfx;
    }
    __syncthreads();
    int prefix = sprefix + texcl;
    int4 e;
    e.x = prefix;
    e.y = prefix + v.x;
    e.z = prefix + v.x + v.y;
    e.w = prefix + v.x + v.y + v.z;
    *(int4*)&cursor[base] = e;
}

// writes sorted-position records (lin, origrow): k_mega Phase A is coalesced.
__global__ void k_scatter(const unsigned* __restrict__ packed, const int* __restrict__ cursor,
                          uint2* __restrict__ recs) {
    int j = blockIdx.x * 256 + threadIdx.x;
    unsigned p = packed[j];
    unsigned lin = p >> OFF_BITS;
    int pos = cursor[lin >> BIN_SHIFT] + (int)(p & ((1u << OFF_BITS) - 1u));
    recs[pos] = make_uint2(lin, (unsigned)j);
}

// ---------- fused fixup + GEMM + LN, direct-from-register nt output ----------
__global__ __launch_bounds__(256) void k_mega(
    const float* __restrict__ feats, const float* __restrict__ weight,
    const float* __restrict__ gamma, const float* __restrict__ beta,
    const int* __restrict__ hist, const int* __restrict__ cursor,
    const uint2* __restrict__ recs, float* __restrict__ out) {
    __shared__ float featb[4][8][CIN];         // 8 KB (wave-private slices)
    __shared__ unsigned slin[PCAP];            // 4 KB
    __shared__ int sperm[PCAP];                // 4 KB
    __shared__ unsigned short vpos[PCAP];      // 2 KB (ascending)
    __shared__ int wsum[4];

    int tid = threadIdx.x;
    int w = tid >> 6, lane = tid & 63;
    int B0 = blockIdx.x * BPB;
    int p0 = cursor[B0];
    int p1 = (B0 + BPB < BINS) ? cursor[B0 + BPB] : N_VOX;
    int npos = p1 - p0;                        // ~Poisson(256), < PCAP

    // Phase A1: coalesced load of records into LDS
    for (int lp = tid; lp < npos; lp += 256) {
        uint2 r = recs[p0 + lp];
        slin[lp] = r.x;
        sperm[lp] = (int)r.y;
    }
    __syncthreads();

    // Phase A2: 2 bins/thread, stable fixup in LDS (key = lin<<19|j) + count
    int2 ch = *(const int2*)&hist[B0 + 2 * tid];
    int2 cc = *(const int2*)&cursor[B0 + 2 * tid];
    int myv = 0;
    #pragma unroll
    for (int bb = 0; bb < 2; bb++) {
        int c  = bb ? ch.y : ch.x;
        int ls = (bb ? cc.y : cc.x) - p0;
        if (c >= 2) {
            for (int i = 1; i < c; i++) {
                unsigned lj = slin[ls + i];
                int pj = sperm[ls + i];
                unsigned long long kj = ((unsigned long long)lj << 19) | (unsigned)pj;
                int m = i - 1;
                while (m >= 0) {
                    unsigned lm = slin[ls + m];
                    int pm = sperm[ls + m];
                    unsigned long long km = ((unsigned long long)lm << 19) | (unsigned)pm;
                    if (km <= kj) break;
                    slin[ls + m + 1] = lm;
                    sperm[ls + m + 1] = pm;
                    m--;
                }
                slin[ls + m + 1] = lj;
                sperm[ls + m + 1] = pj;
            }
        }
        for (int i = 0; i < c; i++)
            myv += ((slin[ls + i] & 0x201u) == 0u) ? 1 : 0;
    }
    // block-exclusive scan of myv (wave shuffle + 1 barrier)
    int incl = myv;
    #pragma unroll
    for (int off = 1; off < 64; off <<= 1) {
        int u = __shfl_up(incl, off);
        if (lane >= off) incl += u;
    }
    if (lane == 63) wsum[w] = incl;
    __syncthreads();
    int s0 = wsum[0], s1 = wsum[1], s2 = wsum[2], s3 = wsum[3];
    int nv = s0 + s1 + s2 + s3;
    int woff = (w > 0 ? s0 : 0) + (w > 1 ? s1 : 0) + (w > 2 ? s2 : 0);
    int basev = woff + incl - myv;
    #pragma unroll
    for (int bb = 0; bb < 2; bb++) {
        int c  = bb ? ch.y : ch.x;
        int ls = (bb ? cc.y : cc.x) - p0;
        for (int i = 0; i < c; i++) {
            int lp = ls + i;
            if ((slin[lp] & 0x201u) == 0u) vpos[basev++] = (unsigned short)lp;
        }
    }
    __syncthreads();

    int half = lane >> 5, l32 = lane & 31;
    float* oidx = out + (size_t)N_VOX * COUT;

    // Phase B: invalid rows -> zeros + (-1) idx, issued early (nt, 512B rows)
    {
        f32x4 z = {0.f, 0.f, 0.f, 0.f};
        for (int lp = w * 2 + half; lp < npos; lp += 8) {
            if (slin[lp] & 0x201u)
                nt_store4(&out[(size_t)(p0 + lp) * COUT + l32 * 4], z);
        }
        f32x4 mi = {-1.f, -1.f, -1.f, -1.f};
        for (int lp = tid; lp < npos; lp += 256) {
            if (slin[lp] & 0x201u)
                nt_store4(&oidx[(size_t)(p0 + lp) * 4], mi);
        }
    }

    // Phase C: GEMM + LN, direct register->nt stores (512B contiguous per row)
    if (nv == 0) return;
    const f32x4* Wg4 = (const f32x4*)weight;   // [64][32] of float4
    f32x4 gv = *(const f32x4*)&gamma[l32 * 4];
    f32x4 bv = *(const f32x4*)&beta[l32 * 4];

    for (int m0 = 0; m0 < nv; m0 += 32) {
        int mb = m0 + w * 8;
        if (mb >= nv) continue;                 // no barriers below: safe
        #pragma unroll
        for (int i = 0; i < 8; i++) {
            int m = mb + i;
            int lp = vpos[(m < nv) ? m : 0];
            featb[w][i][lane] = feats[(size_t)sperm[lp] * CIN + lane];
        }

        f32x4 acc[4];
        #pragma unroll
        for (int i = 0; i < 4; i++) acc[i] = (f32x4){0.f, 0.f, 0.f, 0.f};

        #pragma unroll 4
        for (int k0 = 0; k0 < CIN; k0 += 4) {
            f32x4 wv0 = Wg4[(k0 + 0) * 32 + l32];
            f32x4 wv1 = Wg4[(k0 + 1) * 32 + l32];
            f32x4 wv2 = Wg4[(k0 + 2) * 32 + l32];
            f32x4 wv3 = Wg4[(k0 + 3) * 32 + l32];
            #pragma unroll
            for (int ii = 0; ii < 4; ii++) {
                float4 f = *(float4*)&featb[w][2 * ii + half][k0];
                acc[ii] += f.x * wv0;
                acc[ii] += f.y * wv1;
                acc[ii] += f.z * wv2;
                acc[ii] += f.w * wv3;
            }
        }

        #pragma unroll
        for (int ii = 0; ii < 4; ii++) {
            int m = mb + 2 * ii + half;
            f32x4 a = acc[ii];
            float sm = a.x + a.y + a.z + a.w;
            float sq = a.x * a.x + a.y * a.y + a.z * a.z + a.w * a.w;
            #pragma unroll
            for (int off = 16; off > 0; off >>= 1) {   // reduce within 32-lane half
                sm += __shfl_xor(sm, off);
                sq += __shfl_xor(sq, off);
            }
            float mean = sm * (1.0f / COUT);
            float var  = fmaxf(sq * (1.0f / COUT) - mean * mean, 0.0f);
            float rstd = rsqrtf(var + EPSV);
            if (m < nv) {
                int lp = vpos[m];
                int pos = p0 + lp;
                f32x4 o = (a - mean) * rstd * gv + bv;
                nt_store4(&out[(size_t)pos * COUT + l32 * 4], o);
                if (l32 == 0) {
                    unsigned lin = slin[lp];
                    f32x4 ni;
                    ni.x = (float)(lin >> 21);
                    ni.y = (float)((lin >> 18) & 7u);
                    ni.z = (float)(((lin >> 9) & 511u) >> 1);
                    ni.w = (float)((lin & 511u) >> 1);
                    nt_store4(&oidx[(size_t)pos * 4], ni);
                }
            }
        }
    }
}

extern "C" void kernel_launch(void* const* d_in, const int* in_sizes, int n_in,
                              void* d_out, int out_size, void* d_ws, size_t ws_size,
                              hipStream_t stream) {
    const float* feats  = (const float*)d_in[0];
    const int*   idx    = (const int*)d_in[1];
    const float* weight = (const float*)d_in[2];
    const float* gamma  = (const float*)d_in[3];
    const float* beta   = (const float*)d_in[4];
    float* out = (float*)d_out;

    int* ws = (int*)d_ws;
    int*                hist   = ws;                         // BINS
    int*                ticket = ws + BINS;                  // 1 (+3 pad)
    unsigned long long* tiles  = (unsigned long long*)(ws + BINS + 4);  // NTILES
    int*                cursor = ws + BINS + 4 + 2 * NTILES; // BINS
    unsigned*           packed = (unsigned*)(cursor + BINS); // N
    uint2*              recs   = (uint2*)(packed + N_VOX);   // N x 8B

    k_clear<<<(CLR_4 + 255) / 256, 256, 0, stream>>>(ws);
    k_hist<<<N_VOX / 256, 256, 0, stream>>>(idx, packed, hist);
    k_scan<<<NTILES, 256, 0, stream>>>(hist, cursor, tiles, ticket);
    k_scatter<<<N_VOX / 256, 256, 0, stream>>>(packed, cursor, recs);
    k_mega<<<NBLK, 256, 0, stream>>>(feats, weight, gamma, beta,
                                     hist, cursor, recs, out);
}

// Round 17
// 145.072 us; speedup vs baseline: 1.5152x; 1.1369x over previous
//
#include <hip/hip_runtime.h>
#include <stdint.h>

#define N_VOX   (1 << 19)
#define CIN     64
#define COUT    128
#define BIN_SHIFT 5
#define BINS    (1 << 18)          // (4*8*512*512) >> 5, lambda = 2/bin
#define OFF_BITS 6                 // intra-bin arrival offset (max 63, P~0)
#define BPB     128                // bins per k_mega block (~256 positions)
#define NBLK    (BINS / BPB)       // 2048 blocks
#define NTILES  256                // scan tiles (1024 bins each)
#define PCAP    384                // max positions per block (Poisson(256)+8sig)
#define EPSV    1e-5f

typedef float f32x4 __attribute__((ext_vector_type(4)));

static __device__ __forceinline__ void nt_store4(float* p, f32x4 v) {
    __builtin_nontemporal_store(v, (f32x4*)p);
}

// Established (r15 probe): d_out stores cap ~2.8 TB/s regardless of pattern
// (destination-bound); d_ws absorbs ~6.9 TB/s. Floor: 276 MB d_out ~= 99 us.
// r17: shrink the serialized pre-drain segment — 4x smaller bin metadata
// (shift 5), 4x shorter lookback chain, leaner k_mega Phase A, Phase B
// issued one barrier earlier.
//
// ws ints: hist[BINS] | ticket(1)+pad(3) | tiles[2*NTILES] | cursor[BINS]
//          | packed[N] | recs[2*N]

#define CLR_INTS (BINS + 4 + 2 * NTILES)
#define CLR_4    (CLR_INTS / 4 + 1)

__global__ void k_clear(int* __restrict__ p) {
    int t = blockIdx.x * 256 + threadIdx.x;
    if (t * 4 < CLR_INTS) *(int4*)&p[t * 4] = make_int4(0, 0, 0, 0);
}

__global__ void k_hist(const int* __restrict__ idx, unsigned* __restrict__ packed,
                       int* __restrict__ hist) {
    int j = blockIdx.x * 256 + threadIdx.x;
    int4 v = *(const int4*)&idx[j * 4];
    int lin = ((v.x * 8 + v.y) * 512 + v.z) * 512 + v.w;
    int off = atomicAdd(&hist[lin >> BIN_SHIFT], 1);
    packed[j] = ((unsigned)lin << OFF_BITS) | (unsigned)off;
}

// single-kernel exclusive scan, decoupled lookback, ticket-ordered tiles.
__global__ __launch_bounds__(256) void k_scan(
    const int* __restrict__ hist, int* __restrict__ cursor,
    unsigned long long* __restrict__ tiles, int* __restrict__ ticket) {
    __shared__ int stile;
    __shared__ int wsums[4];
    __shared__ int sprefix;
    int tid = threadIdx.x;
    if (tid == 0) stile = atomicAdd(ticket, 1);
    __syncthreads();
    int tile = stile;
    int base = tile * 1024 + tid * 4;
    int4 v = *(const int4*)&hist[base];
    int t3 = v.x + v.y + v.z + v.w;
    int lane = tid & 63, w = tid >> 6;
    int incl = t3;
    #pragma unroll
    for (int off = 1; off < 64; off <<= 1) {
        int u = __shfl_up(incl, off);
        if (lane >= off) incl += u;
    }
    if (lane == 63) wsums[w] = incl;
    __syncthreads();
    int woff = (w > 0 ? wsums[0] : 0) + (w > 1 ? wsums[1] : 0) + (w > 2 ? wsums[2] : 0);
    int total = wsums[0] + wsums[1] + wsums[2] + wsums[3];
    int texcl = woff + incl - t3;
    if (tid == 0) {
        unsigned long long st = (tile == 0) ? 2ull : 1ull;
        atomicExch(&tiles[tile], (st << 40) | (unsigned long long)(unsigned)total);
        int pfx = 0;
        if (tile > 0) {
            int p = tile - 1;
            while (true) {
                unsigned long long d = atomicAdd(&tiles[p], 0ull);
                unsigned long long st2 = d >> 40;
                if (st2 == 0) { __builtin_amdgcn_s_sleep(2); continue; }
                pfx += (int)(unsigned)(d & 0xFFFFFFFFull);
                if (st2 == 2ull) break;
                p--;
            }
            atomicExch(&tiles[tile],
                       (2ull << 40) | (unsigned long long)(unsigned)(pfx + total));
        }
        sprefix = pfx;
    }
    __syncthreads();
    int prefix = sprefix + texcl;
    int4 e;
    e.x = prefix;
    e.y = prefix + v.x;
    e.z = prefix + v.x + v.y;
    e.w = prefix + v.x + v.y + v.z;
    *(int4*)&cursor[base] = e;
}

// writes sorted-position records (lin, origrow): k_mega Phase A is coalesced.
__global__ void k_scatter(const unsigned* __restrict__ packed, const int* __restrict__ cursor,
                          uint2* __restrict__ recs) {
    int j = blockIdx.x * 256 + threadIdx.x;
    unsigned p = packed[j];
    unsigned lin = p >> OFF_BITS;
    int pos = cursor[lin >> BIN_SHIFT] + (int)(p & ((1u << OFF_BITS) - 1u));
    recs[pos] = make_uint2(lin, (unsigned)j);
}

// ---------- fused fixup + GEMM + LN, direct-from-register nt output ----------
__global__ __launch_bounds__(256) void k_mega(
    const float* __restrict__ feats, const float* __restrict__ weight,
    const float* __restrict__ gamma, const float* __restrict__ beta,
    const int* __restrict__ hist, const int* __restrict__ cursor,
    const uint2* __restrict__ recs, float* __restrict__ out) {
    __shared__ float featb[4][8][CIN];         // 8 KB (wave-private slices)
    __shared__ unsigned slin[PCAP];            // 1.5 KB
    __shared__ int sperm[PCAP];                // 1.5 KB
    __shared__ unsigned short vpos[PCAP];      // 0.75 KB (ascending)
    __shared__ int wsum[4];

    int tid = threadIdx.x;
    int w = tid >> 6, lane = tid & 63;
    int B0 = blockIdx.x * BPB;
    int p0 = cursor[B0];
    int p1 = (B0 + BPB < BINS) ? cursor[B0 + BPB] : N_VOX;
    int npos = p1 - p0;                        // ~Poisson(256), < PCAP

    // Phase A1: coalesced load of records into LDS
    for (int lp = tid; lp < npos; lp += 256) {
        uint2 r = recs[p0 + lp];
        slin[lp] = r.x;
        sperm[lp] = (int)r.y;
    }
    __syncthreads();

    // Phase A2: 1 bin/thread (tid<128), stable fixup in LDS (key = lin<<19|j)
    int c = 0, ls = 0;
    if (tid < BPB) {
        c = hist[B0 + tid];
        ls = cursor[B0 + tid] - p0;
    }
    if (c >= 2) {
        for (int i = 1; i < c; i++) {
            unsigned lj = slin[ls + i];
            int pj = sperm[ls + i];
            unsigned long long kj = ((unsigned long long)lj << 19) | (unsigned)pj;
            int m = i - 1;
            while (m >= 0) {
                unsigned lm = slin[ls + m];
                int pm = sperm[ls + m];
                unsigned long long km = ((unsigned long long)lm << 19) | (unsigned)pm;
                if (km <= kj) break;
                slin[ls + m + 1] = lm;
                sperm[ls + m + 1] = pm;
                m--;
            }
            slin[ls + m + 1] = lj;
            sperm[ls + m + 1] = pj;
        }
    }
    int myv = 0;
    for (int i = 0; i < c; i++)
        myv += ((slin[ls + i] & 0x201u) == 0u) ? 1 : 0;
    // block-exclusive scan of myv (wave shuffle + 1 barrier)
    int incl = myv;
    #pragma unroll
    for (int off = 1; off < 64; off <<= 1) {
        int u = __shfl_up(incl, off);
        if (lane >= off) incl += u;
    }
    if (lane == 63) wsum[w] = incl;
    __syncthreads();                           // slin fixup + wsum visible
    int s0 = wsum[0], s1 = wsum[1], s2 = wsum[2], s3 = wsum[3];
    int nv = s0 + s1 + s2 + s3;
    int woff = (w > 0 ? s0 : 0) + (w > 1 ? s1 : 0) + (w > 2 ? s2 : 0);

    int half = lane >> 5, l32 = lane & 31;
    float* oidx = out + (size_t)N_VOX * COUT;

    // Phase B: invalid rows -> zeros + (-1) idx, issued EARLY (nt, 512B rows)
    {
        f32x4 z = {0.f, 0.f, 0.f, 0.f};
        for (int lp = w * 2 + half; lp < npos; lp += 8) {
            if (slin[lp] & 0x201u)
                nt_store4(&out[(size_t)(p0 + lp) * COUT + l32 * 4], z);
        }
        f32x4 mi = {-1.f, -1.f, -1.f, -1.f};
        for (int lp = tid; lp < npos; lp += 256) {
            if (slin[lp] & 0x201u)
                nt_store4(&oidx[(size_t)(p0 + lp) * 4], mi);
        }
    }

    // build vpos (ascending valid positions)
    int basev = woff + incl - myv;
    for (int i = 0; i < c; i++) {
        int lp = ls + i;
        if ((slin[lp] & 0x201u) == 0u) vpos[basev++] = (unsigned short)lp;
    }
    __syncthreads();

    // Phase C: GEMM + LN, direct register->nt stores (512B contiguous per row)
    if (nv == 0) return;
    const f32x4* Wg4 = (const f32x4*)weight;   // [64][32] of float4
    f32x4 gv = *(const f32x4*)&gamma[l32 * 4];
    f32x4 bv = *(const f32x4*)&beta[l32 * 4];

    for (int m0 = 0; m0 < nv; m0 += 32) {
        int mb = m0 + w * 8;
        if (mb >= nv) continue;                 // no barriers below: safe
        #pragma unroll
        for (int i = 0; i < 8; i++) {
            int m = mb + i;
            int lp = vpos[(m < nv) ? m : 0];
            featb[w][i][lane] = feats[(size_t)sperm[lp] * CIN + lane];
        }

        f32x4 acc[4];
        #pragma unroll
        for (int i = 0; i < 4; i++) acc[i] = (f32x4){0.f, 0.f, 0.f, 0.f};

        #pragma unroll 4
        for (int k0 = 0; k0 < CIN; k0 += 4) {
            f32x4 wv0 = Wg4[(k0 + 0) * 32 + l32];
            f32x4 wv1 = Wg4[(k0 + 1) * 32 + l32];
            f32x4 wv2 = Wg4[(k0 + 2) * 32 + l32];
            f32x4 wv3 = Wg4[(k0 + 3) * 32 + l32];
            #pragma unroll
            for (int ii = 0; ii < 4; ii++) {
                float4 f = *(float4*)&featb[w][2 * ii + half][k0];
                acc[ii] += f.x * wv0;
                acc[ii] += f.y * wv1;
                acc[ii] += f.z * wv2;
                acc[ii] += f.w * wv3;
            }
        }

        #pragma unroll
        for (int ii = 0; ii < 4; ii++) {
            int m = mb + 2 * ii + half;
            f32x4 a = acc[ii];
            float sm = a.x + a.y + a.z + a.w;
            float sq = a.x * a.x + a.y * a.y + a.z * a.z + a.w * a.w;
            #pragma unroll
            for (int off = 16; off > 0; off >>= 1) {   // reduce within 32-lane half
                sm += __shfl_xor(sm, off);
                sq += __shfl_xor(sq, off);
            }
            float mean = sm * (1.0f / COUT);
            float var  = fmaxf(sq * (1.0f / COUT) - mean * mean, 0.0f);
            float rstd = rsqrtf(var + EPSV);
            if (m < nv) {
                int lp = vpos[m];
                int pos = p0 + lp;
                f32x4 o = (a - mean) * rstd * gv + bv;
                nt_store4(&out[(size_t)pos * COUT + l32 * 4], o);
                if (l32 == 0) {
                    unsigned lin = slin[lp];
                    f32x4 ni;
                    ni.x = (float)(lin >> 21);
                    ni.y = (float)((lin >> 18) & 7u);
                    ni.z = (float)(((lin >> 9) & 511u) >> 1);
                    ni.w = (float)((lin & 511u) >> 1);
                    nt_store4(&oidx[(size_t)pos * 4], ni);
                }
            }
        }
    }
}

extern "C" void kernel_launch(void* const* d_in, const int* in_sizes, int n_in,
                              void* d_out, int out_size, void* d_ws, size_t ws_size,
                              hipStream_t stream) {
    const float* feats  = (const float*)d_in[0];
    const int*   idx    = (const int*)d_in[1];
    const float* weight = (const float*)d_in[2];
    const float* gamma  = (const float*)d_in[3];
    const float* beta   = (const float*)d_in[4];
    float* out = (float*)d_out;

    int* ws = (int*)d_ws;
    int*                hist   = ws;                         // BINS
    int*                ticket = ws + BINS;                  // 1 (+3 pad)
    unsigned long long* tiles  = (unsigned long long*)(ws + BINS + 4);  // NTILES
    int*                cursor = ws + BINS + 4 + 2 * NTILES; // BINS
    unsigned*           packed = (unsigned*)(cursor + BINS); // N
    uint2*              recs   = (uint2*)(packed + N_VOX);   // N x 8B

    k_clear<<<(CLR_4 + 255) / 256, 256, 0, stream>>>(ws);
    k_hist<<<N_VOX / 256, 256, 0, stream>>>(idx, packed, hist);
    k_scan<<<NTILES, 256, 0, stream>>>(hist, cursor, tiles, ticket);
    k_scatter<<<N_VOX / 256, 256, 0, stream>>>(packed, cursor, recs);
    k_mega<<<NBLK, 256, 0, stream>>>(feats, weight, gamma, beta,
                                     hist, cursor, recs, out);
}

// Round 18
// 142.057 us; speedup vs baseline: 1.5473x; 1.0212x over previous
//
#include <hip/hip_runtime.h>
#include <stdint.h>

#define N_VOX   (1 << 19)
#define CIN     64
#define COUT    128
#define BIN_SHIFT 5
#define BINS    (1 << 18)          // (4*8*512*512) >> 5, lambda = 2/bin
#define OFF_BITS 6                 // intra-bin arrival offset (max 63, P~0)
#define BPB     128                // bins per k_mega block (~256 positions)
#define NBLK    (BINS / BPB)       // 2048 blocks
#define NTILES  256                // scan tiles (1024 bins each)
#define PCAP    384                // max positions per block (Poisson(256)+8sig)
#define EPSV    1e-5f

typedef float f32x4 __attribute__((ext_vector_type(4)));

static __device__ __forceinline__ void nt_store4(float* p, f32x4 v) {
    __builtin_nontemporal_store(v, (f32x4*)p);
}

// Established: d_out stores ~2.8 TB/s (destination-bound, r15 probe); floor
// ~99us for 276MB. r18: wave-private single-pass dense output — each wave
// owns 1/4 of the block's positions, builds its own valid list (ballot scan),
// and writes its range in ascending order exactly once (LN rows from regs,
// zeros interleaved). 2 barriers/block, stores start right after fixup.
//
// ws ints: hist[BINS] | ticket(1)+pad(3) | tiles[2*NTILES] | cursor[BINS]
//          | packed[N] | recs[2*N]

#define CLR_INTS (BINS + 4 + 2 * NTILES)
#define CLR_4    (CLR_INTS / 4 + 1)

__global__ void k_clear(int* __restrict__ p) {
    int t = blockIdx.x * 256 + threadIdx.x;
    if (t * 4 < CLR_INTS) *(int4*)&p[t * 4] = make_int4(0, 0, 0, 0);
}

__global__ void k_hist(const int* __restrict__ idx, unsigned* __restrict__ packed,
                       int* __restrict__ hist) {
    int j = blockIdx.x * 256 + threadIdx.x;
    int4 v = *(const int4*)&idx[j * 4];
    int lin = ((v.x * 8 + v.y) * 512 + v.z) * 512 + v.w;
    int off = atomicAdd(&hist[lin >> BIN_SHIFT], 1);
    packed[j] = ((unsigned)lin << OFF_BITS) | (unsigned)off;
}

// single-kernel exclusive scan, decoupled lookback, ticket-ordered tiles.
__global__ __launch_bounds__(256) void k_scan(
    const int* __restrict__ hist, int* __restrict__ cursor,
    unsigned long long* __restrict__ tiles, int* __restrict__ ticket) {
    __shared__ int stile;
    __shared__ int wsums[4];
    __shared__ int sprefix;
    int tid = threadIdx.x;
    if (tid == 0) stile = atomicAdd(ticket, 1);
    __syncthreads();
    int tile = stile;
    int base = tile * 1024 + tid * 4;
    int4 v = *(const int4*)&hist[base];
    int t3 = v.x + v.y + v.z + v.w;
    int lane = tid & 63, w = tid >> 6;
    int incl = t3;
    #pragma unroll
    for (int off = 1; off < 64; off <<= 1) {
        int u = __shfl_up(incl, off);
        if (lane >= off) incl += u;
    }
    if (lane == 63) wsums[w] = incl;
    __syncthreads();
    int woff = (w > 0 ? wsums[0] : 0) + (w > 1 ? wsums[1] : 0) + (w > 2 ? wsums[2] : 0);
    int total = wsums[0] + wsums[1] + wsums[2] + wsums[3];
    int texcl = woff + incl - t3;
    if (tid == 0) {
        unsigned long long st = (tile == 0) ? 2ull : 1ull;
        atomicExch(&tiles[tile], (st << 40) | (unsigned long long)(unsigned)total);
        int pfx = 0;
        if (tile > 0) {
            int p = tile - 1;
            while (true) {
                unsigned long long d = atomicAdd(&tiles[p], 0ull);
                unsigned long long st2 = d >> 40;
                if (st2 == 0) { __builtin_amdgcn_s_sleep(2); continue; }
                pfx += (int)(unsigned)(d & 0xFFFFFFFFull);
                if (st2 == 2ull) break;
                p--;
            }
            atomicExch(&tiles[tile],
                       (2ull << 40) | (unsigned long long)(unsigned)(pfx + total));
        }
        sprefix = pfx;
    }
    __syncthreads();
    int prefix = sprefix + texcl;
    int4 e;
    e.x = prefix;
    e.y = prefix + v.x;
    e.z = prefix + v.x + v.y;
    e.w = prefix + v.x + v.y + v.z;
    *(int4*)&cursor[base] = e;
}

// writes sorted-position records (lin, origrow): k_mega Phase A is coalesced.
__global__ void k_scatter(const unsigned* __restrict__ packed, const int* __restrict__ cursor,
                          uint2* __restrict__ recs) {
    int j = blockIdx.x * 256 + threadIdx.x;
    unsigned p = packed[j];
    unsigned lin = p >> OFF_BITS;
    int pos = cursor[lin >> BIN_SHIFT] + (int)(p & ((1u << OFF_BITS) - 1u));
    recs[pos] = make_uint2(lin, (unsigned)j);
}

// ---- fused fixup + GEMM + LN, wave-private single-pass dense output ----
__global__ __launch_bounds__(256) void k_mega(
    const float* __restrict__ feats, const float* __restrict__ weight,
    const float* __restrict__ gamma, const float* __restrict__ beta,
    const int* __restrict__ hist, const int* __restrict__ cursor,
    const uint2* __restrict__ recs, float* __restrict__ out) {
    __shared__ float featb[4][8][CIN];         // 8 KB (wave-private slices)
    __shared__ unsigned slin[PCAP];            // 1.5 KB
    __shared__ int sperm[PCAP];                // 1.5 KB
    __shared__ unsigned short wvpos[4][96];    // 0.75 KB (per-wave valid lists)

    int tid = threadIdx.x;
    int w = tid >> 6, lane = tid & 63;
    int B0 = blockIdx.x * BPB;
    int p0 = cursor[B0];
    int p1 = (B0 + BPB < BINS) ? cursor[B0 + BPB] : N_VOX;
    int npos = p1 - p0;                        // ~Poisson(256), < PCAP

    // Phase A1: coalesced load of records into LDS
    for (int lp = tid; lp < npos; lp += 256) {
        uint2 r = recs[p0 + lp];
        slin[lp] = r.x;
        sperm[lp] = (int)r.y;
    }
    __syncthreads();

    // Phase A2: 1 bin/thread (tid<128), stable fixup in LDS (key = lin<<19|j)
    int c = 0, ls = 0;
    if (tid < BPB) {
        c = hist[B0 + tid];
        ls = cursor[B0 + tid] - p0;
    }
    if (c >= 2) {
        for (int i = 1; i < c; i++) {
            unsigned lj = slin[ls + i];
            int pj = sperm[ls + i];
            unsigned long long kj = ((unsigned long long)lj << 19) | (unsigned)pj;
            int m = i - 1;
            while (m >= 0) {
                unsigned lm = slin[ls + m];
                int pm = sperm[ls + m];
                unsigned long long km = ((unsigned long long)lm << 19) | (unsigned)pm;
                if (km <= kj) break;
                slin[ls + m + 1] = lm;
                sperm[ls + m + 1] = pm;
                m--;
            }
            slin[ls + m + 1] = lj;
            sperm[ls + m + 1] = pj;
        }
    }
    __syncthreads();                           // fixup visible block-wide

    // Wave-private range [r0, r1)
    int Q = (npos + 3) >> 2;
    int r0 = w * Q;
    int r1 = min(npos, r0 + Q);
    int half = lane >> 5, l32 = lane & 31;
    float* oidx = out + (size_t)N_VOX * COUT;

    // build per-wave valid list (ballot scan, order-preserving)
    int wnv = 0;
    for (int base = r0; base < r1; base += 64) {
        int lp = base + lane;
        bool valid = (lp < r1) && ((slin[lp] & 0x201u) == 0u);
        unsigned long long bv = __ballot(valid);
        int rank = __builtin_popcountll(bv & ((1ull << lane) - 1ull));
        if (valid) wvpos[w][wnv + rank] = (unsigned short)lp;
        wnv += __builtin_popcountll(bv);
    }

    // new_idx for this wave's range: ascending, 16B/lane (issued early)
    for (int lp = r0 + lane; lp < r1; lp += 64) {
        unsigned lin = slin[lp];
        f32x4 ni;
        if ((lin & 0x201u) == 0u) {
            ni.x = (float)(lin >> 21);
            ni.y = (float)((lin >> 18) & 7u);
            ni.z = (float)(((lin >> 9) & 511u) >> 1);
            ni.w = (float)((lin & 511u) >> 1);
        } else {
            ni = (f32x4){-1.f, -1.f, -1.f, -1.f};
        }
        nt_store4(&oidx[(size_t)(p0 + lp) * 4], ni);
    }

    f32x4 z = {0.f, 0.f, 0.f, 0.f};
    if (wnv == 0) {                            // whole range invalid
        for (int lp = r0 + half; lp < r1; lp += 2)
            nt_store4(&out[(size_t)(p0 + lp) * COUT + l32 * 4], z);
        return;
    }

    const f32x4* Wg4 = (const f32x4*)weight;   // [64][32] of float4
    f32x4 gv = *(const f32x4*)&gamma[l32 * 4];
    f32x4 bvv = *(const f32x4*)&beta[l32 * 4];
    int wcur = r0;

    for (int mb = 0; mb < wnv; mb += 8) {
        // gather 8 valid rows into wave-private LDS slice
        #pragma unroll
        for (int i = 0; i < 8; i++) {
            int m = mb + i;
            int lp = wvpos[w][(m < wnv) ? m : 0];
            featb[w][i][lane] = feats[(size_t)sperm[lp] * CIN + lane];
        }

        f32x4 acc[4];
        #pragma unroll
        for (int i = 0; i < 4; i++) acc[i] = z;

        #pragma unroll 4
        for (int k0 = 0; k0 < CIN; k0 += 4) {
            f32x4 wv0 = Wg4[(k0 + 0) * 32 + l32];
            f32x4 wv1 = Wg4[(k0 + 1) * 32 + l32];
            f32x4 wv2 = Wg4[(k0 + 2) * 32 + l32];
            f32x4 wv3 = Wg4[(k0 + 3) * 32 + l32];
            #pragma unroll
            for (int ii = 0; ii < 4; ii++) {
                float4 f = *(float4*)&featb[w][2 * ii + half][k0];
                acc[ii] += f.x * wv0;
                acc[ii] += f.y * wv1;
                acc[ii] += f.z * wv2;
                acc[ii] += f.w * wv3;
            }
        }

        // LN + store valid rows of this batch (each half owns 4 rows)
        #pragma unroll
        for (int ii = 0; ii < 4; ii++) {
            int m = mb + 2 * ii + half;
            f32x4 a = acc[ii];
            float sm = a.x + a.y + a.z + a.w;
            float sq = a.x * a.x + a.y * a.y + a.z * a.z + a.w * a.w;
            #pragma unroll
            for (int off = 16; off > 0; off >>= 1) {   // reduce within 32-lane half
                sm += __shfl_xor(sm, off);
                sq += __shfl_xor(sq, off);
            }
            float mean = sm * (1.0f / COUT);
            float var  = fmaxf(sq * (1.0f / COUT) - mean * mean, 0.0f);
            float rstd = rsqrtf(var + EPSV);
            if (m < wnv) {
                int pos = p0 + wvpos[w][m];
                f32x4 o = (a - mean) * rstd * gv + bvv;
                nt_store4(&out[(size_t)pos * COUT + l32 * 4], o);
            }
        }

        // zeros for invalid rows in window [wcur, wnext), split by parity
        int wnext = (mb + 8 < wnv) ? (int)wvpos[w][mb + 8] : r1;
        for (int lp = wcur + half; lp < wnext; lp += 2) {
            if (slin[lp] & 0x201u)
                nt_store4(&out[(size_t)(p0 + lp) * COUT + l32 * 4], z);
        }
        wcur = wnext;
    }
}

extern "C" void kernel_launch(void* const* d_in, const int* in_sizes, int n_in,
                              void* d_out, int out_size, void* d_ws, size_t ws_size,
                              hipStream_t stream) {
    const float* feats  = (const float*)d_in[0];
    const int*   idx    = (const int*)d_in[1];
    const float* weight = (const float*)d_in[2];
    const float* gamma  = (const float*)d_in[3];
    const float* beta   = (const float*)d_in[4];
    float* out = (float*)d_out;

    int* ws = (int*)d_ws;
    int*                hist   = ws;                         // BINS
    int*                ticket = ws + BINS;                  // 1 (+3 pad)
    unsigned long long* tiles  = (unsigned long long*)(ws + BINS + 4);  // NTILES
    int*                cursor = ws + BINS + 4 + 2 * NTILES; // BINS
    unsigned*           packed = (unsigned*)(cursor + BINS); // N
    uint2*              recs   = (uint2*)(packed + N_VOX);   // N x 8B

    k_clear<<<(CLR_4 + 255) / 256, 256, 0, stream>>>(ws);
    k_hist<<<N_VOX / 256, 256, 0, stream>>>(idx, packed, hist);
    k_scan<<<NTILES, 256, 0, stream>>>(hist, cursor, tiles, ticket);
    k_scatter<<<N_VOX / 256, 256, 0, stream>>>(packed, cursor, recs);
    k_mega<<<NBLK, 256, 0, stream>>>(feats, weight, gamma, beta,
                                     hist, cursor, recs, out);
}

// Round 19
// 140.508 us; speedup vs baseline: 1.5644x; 1.0110x over previous
//
#include <hip/hip_runtime.h>
#include <stdint.h>

#define N_VOX   (1 << 19)
#define CIN     64
#define COUT    128
#define BIN_SHIFT 6
#define BINS    (1 << 17)          // (4*8*512*512) >> 6, lambda = 4/bin
#define OFF_BITS 7                 // intra-bin arrival offset (max 127, P~0)
#define BPB     64                 // bins per k_mega block (~256 positions)
#define NBLK    (BINS / BPB)       // 2048 blocks
#define NTILES  128                // scan tiles (1024 bins each)
#define PCAP    384                // max positions per block (Poisson(256)+8sig)
#define EPSV    1e-5f

typedef float f32x4 __attribute__((ext_vector_type(4)));

static __device__ __forceinline__ void nt_store4(float* p, f32x4 v) {
    __builtin_nontemporal_store(v, (f32x4*)p);
}

// Established: d_out stores ~2.8 TB/s (destination wall, r15 differential
// probe); drain floor ~97us for 276MB. Budget r18: 97 drain + ~24 chain +
// ~10 mega-head + ramps = 142. r19: halve chain metadata again (shift 6),
// hist clears scan's tiles/ticket, 1-bin/thread fixup.
//
// ws ints: hist[BINS] | ticket(1)+pad(3) | tiles[2*NTILES] | cursor[BINS]
//          | packed[N] | recs[2*N]

#define CLR_INTS BINS              // k_clear: hist only
#define META_INTS (4 + 2 * NTILES) // ticket + tiles, cleared inside k_hist

__global__ void k_clear(int* __restrict__ p) {
    int t = blockIdx.x * 256 + threadIdx.x;
    if (t * 4 < CLR_INTS) *(int4*)&p[t * 4] = make_int4(0, 0, 0, 0);
}

__global__ void k_hist(const int* __restrict__ idx, unsigned* __restrict__ packed,
                       int* __restrict__ hist, int* __restrict__ meta) {
    int gid = blockIdx.x * 256 + threadIdx.x;
    if (gid < META_INTS) meta[gid] = 0;        // ticket + tiles (read by k_scan)
    int4 v = *(const int4*)&idx[gid * 4];
    int lin = ((v.x * 8 + v.y) * 512 + v.z) * 512 + v.w;
    int off = atomicAdd(&hist[lin >> BIN_SHIFT], 1);
    packed[gid] = ((unsigned)lin << OFF_BITS) | (unsigned)off;
}

// single-kernel exclusive scan, decoupled lookback, ticket-ordered tiles.
__global__ __launch_bounds__(256) void k_scan(
    const int* __restrict__ hist, int* __restrict__ cursor,
    unsigned long long* __restrict__ tiles, int* __restrict__ ticket) {
    __shared__ int stile;
    __shared__ int wsums[4];
    __shared__ int sprefix;
    int tid = threadIdx.x;
    if (tid == 0) stile = atomicAdd(ticket, 1);
    __syncthreads();
    int tile = stile;
    int base = tile * 1024 + tid * 4;
    int4 v = *(const int4*)&hist[base];
    int t3 = v.x + v.y + v.z + v.w;
    int lane = tid & 63, w = tid >> 6;
    int incl = t3;
    #pragma unroll
    for (int off = 1; off < 64; off <<= 1) {
        int u = __shfl_up(incl, off);
        if (lane >= off) incl += u;
    }
    if (lane == 63) wsums[w] = incl;
    __syncthreads();
    int woff = (w > 0 ? wsums[0] : 0) + (w > 1 ? wsums[1] : 0) + (w > 2 ? wsums[2] : 0);
    int total = wsums[0] + wsums[1] + wsums[2] + wsums[3];
    int texcl = woff + incl - t3;
    if (tid == 0) {
        unsigned long long st = (tile == 0) ? 2ull : 1ull;
        atomicExch(&tiles[tile], (st << 40) | (unsigned long long)(unsigned)total);
        int pfx = 0;
        if (tile > 0) {
            int p = tile - 1;
            while (true) {
                unsigned long long d = atomicAdd(&tiles[p], 0ull);
                unsigned long long st2 = d >> 40;
                if (st2 == 0) { __builtin_amdgcn_s_sleep(2); continue; }
                pfx += (int)(unsigned)(d & 0xFFFFFFFFull);
                if (st2 == 2ull) break;
                p--;
            }
            atomicExch(&tiles[tile],
                       (2ull << 40) | (unsigned long long)(unsigned)(pfx + total));
        }
        sprefix = pfx;
    }
    __syncthreads();
    int prefix = sprefix + texcl;
    int4 e;
    e.x = prefix;
    e.y = prefix + v.x;
    e.z = prefix + v.x + v.y;
    e.w = prefix + v.x + v.y + v.z;
    *(int4*)&cursor[base] = e;
}

// writes sorted-position records (lin, origrow): k_mega Phase A is coalesced.
__global__ void k_scatter(const unsigned* __restrict__ packed, const int* __restrict__ cursor,
                          uint2* __restrict__ recs) {
    int j = blockIdx.x * 256 + threadIdx.x;
    unsigned p = packed[j];
    unsigned lin = p >> OFF_BITS;
    int pos = cursor[lin >> BIN_SHIFT] + (int)(p & ((1u << OFF_BITS) - 1u));
    recs[pos] = make_uint2(lin, (unsigned)j);
}

// ---- fused fixup + GEMM + LN, wave-private single-pass dense output ----
__global__ __launch_bounds__(256) void k_mega(
    const float* __restrict__ feats, const float* __restrict__ weight,
    const float* __restrict__ gamma, const float* __restrict__ beta,
    const int* __restrict__ hist, const int* __restrict__ cursor,
    const uint2* __restrict__ recs, float* __restrict__ out) {
    __shared__ float featb[4][8][CIN];         // 8 KB (wave-private slices)
    __shared__ unsigned slin[PCAP];            // 1.5 KB
    __shared__ int sperm[PCAP];                // 1.5 KB
    __shared__ unsigned short wvpos[4][96];    // 0.75 KB (per-wave valid lists)

    int tid = threadIdx.x;
    int w = tid >> 6, lane = tid & 63;
    int B0 = blockIdx.x * BPB;
    int p0 = cursor[B0];
    int p1 = (B0 + BPB < BINS) ? cursor[B0 + BPB] : N_VOX;
    int npos = p1 - p0;                        // ~Poisson(256), < PCAP

    // Phase A1: coalesced load of records into LDS
    for (int lp = tid; lp < npos; lp += 256) {
        uint2 r = recs[p0 + lp];
        slin[lp] = r.x;
        sperm[lp] = (int)r.y;
    }
    __syncthreads();

    // Phase A2: 1 bin/thread (tid<64), stable fixup in LDS (key = lin<<19|j)
    int c = 0, ls = 0;
    if (tid < BPB) {
        c = hist[B0 + tid];
        ls = cursor[B0 + tid] - p0;
    }
    if (c >= 2) {
        for (int i = 1; i < c; i++) {
            unsigned lj = slin[ls + i];
            int pj = sperm[ls + i];
            unsigned long long kj = ((unsigned long long)lj << 19) | (unsigned)pj;
            int m = i - 1;
            while (m >= 0) {
                unsigned lm = slin[ls + m];
                int pm = sperm[ls + m];
                unsigned long long km = ((unsigned long long)lm << 19) | (unsigned)pm;
                if (km <= kj) break;
                slin[ls + m + 1] = lm;
                sperm[ls + m + 1] = pm;
                m--;
            }
            slin[ls + m + 1] = lj;
            sperm[ls + m + 1] = pj;
        }
    }
    __syncthreads();                           // fixup visible block-wide

    // Wave-private range [r0, r1)
    int Q = (npos + 3) >> 2;
    int r0 = w * Q;
    int r1 = min(npos, r0 + Q);
    int half = lane >> 5, l32 = lane & 31;
    float* oidx = out + (size_t)N_VOX * COUT;

    // build per-wave valid list (ballot scan, order-preserving)
    int wnv = 0;
    for (int base = r0; base < r1; base += 64) {
        int lp = base + lane;
        bool valid = (lp < r1) && ((slin[lp] & 0x201u) == 0u);
        unsigned long long bv = __ballot(valid);
        int rank = __builtin_popcountll(bv & ((1ull << lane) - 1ull));
        if (valid) wvpos[w][wnv + rank] = (unsigned short)lp;
        wnv += __builtin_popcountll(bv);
    }

    // new_idx for this wave's range: ascending, 16B/lane (issued early)
    for (int lp = r0 + lane; lp < r1; lp += 64) {
        unsigned lin = slin[lp];
        f32x4 ni;
        if ((lin & 0x201u) == 0u) {
            ni.x = (float)(lin >> 21);
            ni.y = (float)((lin >> 18) & 7u);
            ni.z = (float)(((lin >> 9) & 511u) >> 1);
            ni.w = (float)((lin & 511u) >> 1);
        } else {
            ni = (f32x4){-1.f, -1.f, -1.f, -1.f};
        }
        nt_store4(&oidx[(size_t)(p0 + lp) * 4], ni);
    }

    f32x4 z = {0.f, 0.f, 0.f, 0.f};
    if (wnv == 0) {                            // whole range invalid
        for (int lp = r0 + half; lp < r1; lp += 2)
            nt_store4(&out[(size_t)(p0 + lp) * COUT + l32 * 4], z);
        return;
    }

    const f32x4* Wg4 = (const f32x4*)weight;   // [64][32] of float4
    f32x4 gv = *(const f32x4*)&gamma[l32 * 4];
    f32x4 bvv = *(const f32x4*)&beta[l32 * 4];
    int wcur = r0;

    for (int mb = 0; mb < wnv; mb += 8) {
        // gather 8 valid rows into wave-private LDS slice
        #pragma unroll
        for (int i = 0; i < 8; i++) {
            int m = mb + i;
            int lp = wvpos[w][(m < wnv) ? m : 0];
            featb[w][i][lane] = feats[(size_t)sperm[lp] * CIN + lane];
        }

        f32x4 acc[4];
        #pragma unroll
        for (int i = 0; i < 4; i++) acc[i] = z;

        #pragma unroll 4
        for (int k0 = 0; k0 < CIN; k0 += 4) {
            f32x4 wv0 = Wg4[(k0 + 0) * 32 + l32];
            f32x4 wv1 = Wg4[(k0 + 1) * 32 + l32];
            f32x4 wv2 = Wg4[(k0 + 2) * 32 + l32];
            f32x4 wv3 = Wg4[(k0 + 3) * 32 + l32];
            #pragma unroll
            for (int ii = 0; ii < 4; ii++) {
                float4 f = *(float4*)&featb[w][2 * ii + half][k0];
                acc[ii] += f.x * wv0;
                acc[ii] += f.y * wv1;
                acc[ii] += f.z * wv2;
                acc[ii] += f.w * wv3;
            }
        }

        // LN + store valid rows of this batch (each half owns 4 rows)
        #pragma unroll
        for (int ii = 0; ii < 4; ii++) {
            int m = mb + 2 * ii + half;
            f32x4 a = acc[ii];
            float sm = a.x + a.y + a.z + a.w;
            float sq = a.x * a.x + a.y * a.y + a.z * a.z + a.w * a.w;
            #pragma unroll
            for (int off = 16; off > 0; off >>= 1) {   // reduce within 32-lane half
                sm += __shfl_xor(sm, off);
                sq += __shfl_xor(sq, off);
            }
            float mean = sm * (1.0f / COUT);
            float var  = fmaxf(sq * (1.0f / COUT) - mean * mean, 0.0f);
            float rstd = rsqrtf(var + EPSV);
            if (m < wnv) {
                int pos = p0 + wvpos[w][m];
                f32x4 o = (a - mean) * rstd * gv + bvv;
                nt_store4(&out[(size_t)pos * COUT + l32 * 4], o);
            }
        }

        // zeros for invalid rows in window [wcur, wnext), split by parity
        int wnext = (mb + 8 < wnv) ? (int)wvpos[w][mb + 8] : r1;
        for (int lp = wcur + half; lp < wnext; lp += 2) {
            if (slin[lp] & 0x201u)
                nt_store4(&out[(size_t)(p0 + lp) * COUT + l32 * 4], z);
        }
        wcur = wnext;
    }
}

extern "C" void kernel_launch(void* const* d_in, const int* in_sizes, int n_in,
                              void* d_out, int out_size, void* d_ws, size_t ws_size,
                              hipStream_t stream) {
    const float* feats  = (const float*)d_in[0];
    const int*   idx    = (const int*)d_in[1];
    const float* weight = (const float*)d_in[2];
    const float* gamma  = (const float*)d_in[3];
    const float* beta   = (const float*)d_in[4];
    float* out = (float*)d_out;

    int* ws = (int*)d_ws;
    int*                hist   = ws;                         // BINS
    int*                meta   = ws + BINS;                  // ticket + tiles
    int*                ticket = meta;                       // 1 (+3 pad)
    unsigned long long* tiles  = (unsigned long long*)(meta + 4);       // NTILES
    int*                cursor = ws + BINS + META_INTS;      // BINS
    unsigned*           packed = (unsigned*)(cursor + BINS); // N
    uint2*              recs   = (uint2*)(packed + N_VOX);   // N x 8B

    k_clear<<<(CLR_INTS / 4 + 255) / 256, 256, 0, stream>>>(hist);
    k_hist<<<N_VOX / 256, 256, 0, stream>>>(idx, packed, hist, meta);
    k_scan<<<NTILES, 256, 0, stream>>>(hist, cursor, tiles, ticket);
    k_scatter<<<N_VOX / 256, 256, 0, stream>>>(packed, cursor, recs);
    k_mega<<<NBLK, 256, 0, stream>>>(feats, weight, gamma, beta,
                                     hist, cursor, recs, out);
}